// Round 5
// baseline (293.104 us; speedup 1.0000x reference)
//
#include <hip/hip_runtime.h>
#include <math.h>

#define N_NODES 32768
#define E_EDGES 262144
#define NFEAT   512
#define NHID    256
#define NCLASS  40
#define EPSV    0.1f
#define VLEN    1024
#define WLEN    32

typedef __attribute__((ext_vector_type(8))) short bf16x8;
typedef __attribute__((ext_vector_type(4))) float f32x4;
typedef __attribute__((ext_vector_type(4))) int i32x4;
typedef __attribute__((ext_vector_type(8))) unsigned short us8;

__device__ inline unsigned short f2bf(float f) {
    unsigned int u = __builtin_bit_cast(unsigned int, f);
    return (unsigned short)((u + 0x7FFFu + ((u >> 16) & 1u)) >> 16);
}
__device__ inline float bf2f(unsigned short h) {
    unsigned int u = ((unsigned int)h) << 16;
    return __builtin_bit_cast(float, u);
}

// truncation split of a pair of fp32 into packed bf16 hi and lo words.
// hi = trunc_bf16(x) (exact residual), lo = trunc_bf16(x - hi); |x-(hi+lo)| < 2^-14 |x|.
__device__ inline void split_pair(float a, float b, unsigned& hi, unsigned& lo) {
    unsigned ua = __builtin_bit_cast(unsigned, a);
    unsigned ub = __builtin_bit_cast(unsigned, b);
    unsigned ha = ua & 0xFFFF0000u, hb = ub & 0xFFFF0000u;
    hi = (ha >> 16) | hb;
    float la = a - __builtin_bit_cast(float, ha);
    float lb = b - __builtin_bit_cast(float, hb);
    unsigned ula = __builtin_bit_cast(unsigned, la);
    unsigned ulb = __builtin_bit_cast(unsigned, lb);
    lo = (ula >> 16) | (ulb & 0xFFFF0000u);
}

// ---------------- init: top=1, cnt=0, cur=0 ----------------
__global__ void init_kernel(float* __restrict__ top, int* __restrict__ cnt,
                            int* __restrict__ cur) {
    int i = blockIdx.x * 256 + threadIdx.x;
    top[i] = 1.0f;
    cnt[i] = 0;
    cur[i] = 0;
}

// ---------------- count in-degree ----------------
__global__ void count_kernel(const int* __restrict__ dst, int* __restrict__ cnt) {
    int e = blockIdx.x * 256 + threadIdx.x;
    atomicAdd(&cnt[dst[e]], 1);
}

// ---------------- exclusive prefix sum over 32768 counts (1 block) ----------------
__global__ __launch_bounds__(1024) void scan_kernel(const int* __restrict__ cnt,
                                                    int* __restrict__ off) {
    __shared__ int part[1024];
    int t = threadIdx.x;
    int base = t * 32;
    int local[32];
    int s = 0;
#pragma unroll
    for (int i = 0; i < 32; ++i) { local[i] = s; s += cnt[base + i]; }
    part[t] = s;
    __syncthreads();
    for (int d = 1; d < 1024; d <<= 1) {
        int v = (t >= d) ? part[t - d] : 0;
        __syncthreads();
        part[t] += v;
        __syncthreads();
    }
    int prev = (t == 0) ? 0 : part[t - 1];
#pragma unroll
    for (int i = 0; i < 32; ++i) off[base + i] = prev + local[i];
    if (t == 1023) off[N_NODES] = prev + s;
}

// ---------------- scatter edges into CSR slots (store src, dst, eid) ----------------
__global__ void scatter_kernel(const int* __restrict__ src, const int* __restrict__ dst,
                               const int* __restrict__ off, int* __restrict__ cur,
                               int* __restrict__ csr_src, int* __restrict__ csr_dst,
                               int* __restrict__ csr_eid) {
    int e = blockIdx.x * 256 + threadIdx.x;
    int d = dst[e];
    int p = atomicAdd(&cur[d], 1);
    int k = off[d] + p;
    csr_src[k] = src[e];
    csr_dst[k] = d;
    csr_eid[k] = e;
}

// ---------------- split Ws into bf16 hi/lo (once, RNE) ----------------
__global__ void wsplit_kernel(const float* __restrict__ Ws,
                              unsigned short* __restrict__ Whi,
                              unsigned short* __restrict__ Wlo) {
    int i = blockIdx.x * 256 + threadIdx.x;   // float4 index
    float4 v = ((const float4*)Ws)[i];
    ushort4 hh, ll;
    hh.x = f2bf(v.x); ll.x = f2bf(v.x - bf2f(hh.x));
    hh.y = f2bf(v.y); ll.y = f2bf(v.y - bf2f(hh.y));
    hh.z = f2bf(v.z); ll.z = f2bf(v.z - bf2f(hh.z));
    hh.w = f2bf(v.w); ll.w = f2bf(v.w - bf2f(hh.w));
    ((ushort4*)Whi)[i] = hh;
    ((ushort4*)Wlo)[i] = ll;
}

// ---------------- h0 = relu(x @ Ws^T + b), LDS-free direct-fragment MFMA ----------------
// 4 waves/block; wave w owns 64 rows x cols [w*64, w*64+64). No barriers, no LDS.
// A fragments: 8 consecutive fp32 of one x row per lane (full 128B line per 4 lanes),
// truncation-split to bf16 hi/lo in registers. B fragments: 16B of L2-resident Whi/Wlo.
__global__ __launch_bounds__(256) void gemm_direct(
        const float* __restrict__ x, const unsigned short* __restrict__ Whi,
        const unsigned short* __restrict__ Wlo, const float* __restrict__ b,
        float* __restrict__ h0) {
    int tid  = threadIdx.x;
    int w    = tid >> 6;
    int lane = tid & 63;
    int m16  = lane & 15;
    int kblk = lane >> 4;
    int row0 = blockIdx.x * 64;
    int colbase = w * 64;

    f32x4 acc[4][4];
#pragma unroll
    for (int mr = 0; mr < 4; ++mr)
#pragma unroll
        for (int nr = 0; nr < 4; ++nr)
#pragma unroll
            for (int e = 0; e < 4; ++e) acc[mr][nr][e] = 0.f;

#pragma unroll 2
    for (int kt = 0; kt < NFEAT; kt += 32) {
        int kf = kt + kblk * 8;
        bf16x8 bh[4], bl[4];
#pragma unroll
        for (int nr = 0; nr < 4; ++nr) {
            size_t boff = (size_t)(colbase + nr * 16 + m16) * NFEAT + kf;
            bh[nr] = *(const bf16x8*)&Whi[boff];
            bl[nr] = *(const bf16x8*)&Wlo[boff];
        }
#pragma unroll
        for (int mr = 0; mr < 4; ++mr) {
            const float* ap = &x[(size_t)(row0 + mr * 16 + m16) * NFEAT + kf];
            float4 v0 = *(const float4*)ap;
            float4 v1 = *(const float4*)(ap + 4);
            unsigned h01, h23, h45, h67, l01, l23, l45, l67;
            split_pair(v0.x, v0.y, h01, l01);
            split_pair(v0.z, v0.w, h23, l23);
            split_pair(v1.x, v1.y, h45, l45);
            split_pair(v1.z, v1.w, h67, l67);
            i32x4 hv = {(int)h01, (int)h23, (int)h45, (int)h67};
            i32x4 lv = {(int)l01, (int)l23, (int)l45, (int)l67};
            bf16x8 ah  = __builtin_bit_cast(bf16x8, hv);
            bf16x8 alo = __builtin_bit_cast(bf16x8, lv);
#pragma unroll
            for (int nr = 0; nr < 4; ++nr) {
                acc[mr][nr] = __builtin_amdgcn_mfma_f32_16x16x32_bf16(ah,  bh[nr], acc[mr][nr], 0, 0, 0);
                acc[mr][nr] = __builtin_amdgcn_mfma_f32_16x16x32_bf16(ah,  bl[nr], acc[mr][nr], 0, 0, 0);
                acc[mr][nr] = __builtin_amdgcn_mfma_f32_16x16x32_bf16(alo, bh[nr], acc[mr][nr], 0, 0, 0);
            }
        }
    }
#pragma unroll
    for (int nr = 0; nr < 4; ++nr) {
        int col = colbase + nr * 16 + m16;
        float bias = b[col];
#pragma unroll
        for (int mr = 0; mr < 4; ++mr) {
#pragma unroll
            for (int r = 0; r < 4; ++r) {
                int row = row0 + mr * 16 + kblk * 4 + r;
                float v = acc[nr < 0 ? 0 : mr][nr][r] + bias;   // (guard folded away)
                v = acc[mr][nr][r] + bias;
                h0[(size_t)row * NHID + col] = v > 0.f ? v : 0.f;
            }
        }
    }
}

// ---------------- al[i] = h[i]·attl, ar[i] = h[i]·attr ----------------
__global__ __launch_bounds__(256) void dots_kernel(
        const float* __restrict__ h, const float* __restrict__ attl,
        const float* __restrict__ attr_, float* __restrict__ al, float* __restrict__ ar) {
    int node = blockIdx.x * 4 + (threadIdx.x >> 6);
    int lane = threadIdx.x & 63;
    float4 hv = *(const float4*)&h[(size_t)node * NHID + lane * 4];
    float4 lv = *(const float4*)&attl[lane * 4];
    float4 rv = *(const float4*)&attr_[lane * 4];
    float sl = hv.x * lv.x + hv.y * lv.y + hv.z * lv.z + hv.w * lv.w;
    float sr = hv.x * rv.x + hv.y * rv.y + hv.z * rv.z + hv.w * rv.w;
#pragma unroll
    for (int off = 32; off; off >>= 1) {
        sl += __shfl_down(sl, off);
        sr += __shfl_down(sr, off);
    }
    if (lane == 0) { al[node] = sl; ar[node] = sr; }
}

// ---------------- per-slot coefficient, CSR order (coalesced) ----------------
__global__ void coefcsr_kernel(const int* __restrict__ csr_src, const int* __restrict__ csr_dst,
                               const int* __restrict__ csr_eid, const float* __restrict__ eattr,
                               const float* __restrict__ top, const float* __restrict__ al,
                               const float* __restrict__ ar, float* __restrict__ csr_coef) {
    int k = blockIdx.x * 256 + threadIdx.x;
    int s = csr_src[k], d = csr_dst[k];
    float w = eattr[csr_eid[k]] * top[s] * top[d];
    csr_coef[k] = (w == 0.f) ? 0.f : tanhf(al[s] + ar[d]) * w;
}

// ---------------- gather: h_out[d] = (sum coef*h_in[src] + eps*h0[d]) * top[d]; nrm ----------------
__global__ __launch_bounds__(256) void gather_kernel(
        const int* __restrict__ csr_src, const int* __restrict__ off,
        const float* __restrict__ csr_coef, const float* __restrict__ h_in,
        const float* __restrict__ h0, const float* __restrict__ top,
        float* __restrict__ h_out, float* __restrict__ nrm) {
    int node = blockIdx.x * 4 + (threadIdx.x >> 6);
    int lane = threadIdx.x & 63;
    size_t base = (size_t)node * NHID + lane * 4;
    float t = top[node];
    if (t == 0.f) {
        *(float4*)&h_out[base] = make_float4(0.f, 0.f, 0.f, 0.f);
        if (lane == 0) nrm[node] = 0.f;
        return;
    }
    int k0 = off[node], k1 = off[node + 1];
    float4 acc = make_float4(0.f, 0.f, 0.f, 0.f);
    int k = k0;
    for (; k + 3 < k1; k += 4) {
        float c0 = csr_coef[k],     c1 = csr_coef[k + 1];
        float c2 = csr_coef[k + 2], c3 = csr_coef[k + 3];
        int   s0 = csr_src[k],      s1 = csr_src[k + 1];
        int   s2 = csr_src[k + 2],  s3 = csr_src[k + 3];
        if (c0 != 0.f && c1 != 0.f && c2 != 0.f && c3 != 0.f) {
            float4 v0 = *(const float4*)&h_in[(size_t)s0 * NHID + lane * 4];
            float4 v1 = *(const float4*)&h_in[(size_t)s1 * NHID + lane * 4];
            float4 v2 = *(const float4*)&h_in[(size_t)s2 * NHID + lane * 4];
            float4 v3 = *(const float4*)&h_in[(size_t)s3 * NHID + lane * 4];
            acc.x += c0 * v0.x + c1 * v1.x + c2 * v2.x + c3 * v3.x;
            acc.y += c0 * v0.y + c1 * v1.y + c2 * v2.y + c3 * v3.y;
            acc.z += c0 * v0.z + c1 * v1.z + c2 * v2.z + c3 * v3.z;
            acc.w += c0 * v0.w + c1 * v1.w + c2 * v2.w + c3 * v3.w;
        } else {
            if (c0 != 0.f) { float4 v = *(const float4*)&h_in[(size_t)s0 * NHID + lane * 4];
                acc.x += c0 * v.x; acc.y += c0 * v.y; acc.z += c0 * v.z; acc.w += c0 * v.w; }
            if (c1 != 0.f) { float4 v = *(const float4*)&h_in[(size_t)s1 * NHID + lane * 4];
                acc.x += c1 * v.x; acc.y += c1 * v.y; acc.z += c1 * v.z; acc.w += c1 * v.w; }
            if (c2 != 0.f) { float4 v = *(const float4*)&h_in[(size_t)s2 * NHID + lane * 4];
                acc.x += c2 * v.x; acc.y += c2 * v.y; acc.z += c2 * v.z; acc.w += c2 * v.w; }
            if (c3 != 0.f) { float4 v = *(const float4*)&h_in[(size_t)s3 * NHID + lane * 4];
                acc.x += c3 * v.x; acc.y += c3 * v.y; acc.z += c3 * v.z; acc.w += c3 * v.w; }
        }
    }
    for (; k < k1; ++k) {
        float c = csr_coef[k];
        if (c != 0.f) {
            int s = csr_src[k];
            float4 v = *(const float4*)&h_in[(size_t)s * NHID + lane * 4];
            acc.x += c * v.x; acc.y += c * v.y; acc.z += c * v.z; acc.w += c * v.w;
        }
    }
    float4 z = *(const float4*)&h0[base];
    float4 v;
    v.x = acc.x + EPSV * z.x;
    v.y = acc.y + EPSV * z.y;
    v.z = acc.z + EPSV * z.z;
    v.w = acc.w + EPSV * z.w;
    *(float4*)&h_out[base] = v;
    float ss = v.x * v.x + v.y * v.y + v.z * v.z + v.w * v.w;
#pragma unroll
    for (int o = 32; o; o >>= 1) ss += __shfl_down(ss, o);
    if (lane == 0) nrm[node] = sqrtf(ss);
}

// ---------------- per-column stable top-k ----------------
__global__ __launch_bounds__(1024) void topk_kernel(
        const float* __restrict__ nrm, float* __restrict__ top, int drop_from) {
    __shared__ float s[VLEN];
    int c = blockIdx.x;
    int r = threadIdx.x;
    float v = nrm[r * WLEN + c];
    s[r] = v;
    __syncthreads();
    int cnt = 0;
    for (int r2 = 0; r2 < VLEN; ++r2) {
        float v2 = s[r2];
        cnt += (v2 > v) || (v2 == v && r2 < r);
    }
    if (cnt >= drop_from) top[r * WLEN + c] = 0.f;
}

// ---------------- out = (h @ We^T + be) * top via split-bf16 MFMA ----------------
#define ASTR 40
#define OBSTR 264
__global__ __launch_bounds__(256) void out_mfma(
        const float* __restrict__ h, const float* __restrict__ We,
        const float* __restrict__ be, const float* __restrict__ top,
        float* __restrict__ out) {
    __shared__ unsigned short Bh[48 * OBSTR];
    __shared__ unsigned short Bl[48 * OBSTR];
    __shared__ unsigned short Ah[64 * ASTR];
    __shared__ unsigned short Al[64 * ASTR];
    int tid  = threadIdx.x;
    int w    = tid >> 6;
    int lane = tid & 63;
    int m16  = lane & 15;
    int kblk = lane >> 4;
    int row0 = blockIdx.x * 64;

    for (int i = tid; i < 48 * 64; i += 256) {
        int r = i >> 6, k4 = i & 63;
        float4 v = (r < NCLASS) ? *(const float4*)&We[r * NHID + k4 * 4]
                                : make_float4(0.f, 0.f, 0.f, 0.f);
        ushort4 hh, ll;
        hh.x = f2bf(v.x); ll.x = f2bf(v.x - bf2f(hh.x));
        hh.y = f2bf(v.y); ll.y = f2bf(v.y - bf2f(hh.y));
        hh.z = f2bf(v.z); ll.z = f2bf(v.z - bf2f(hh.z));
        hh.w = f2bf(v.w); ll.w = f2bf(v.w - bf2f(hh.w));
        *(ushort4*)&Bh[r * OBSTR + k4 * 4] = hh;
        *(ushort4*)&Bl[r * OBSTR + k4 * 4] = ll;
    }

    f32x4 acc[3];
#pragma unroll
    for (int nr = 0; nr < 3; ++nr)
#pragma unroll
        for (int e = 0; e < 4; ++e) acc[nr][e] = 0.f;

    for (int kt = 0; kt < NHID; kt += 32) {
#pragma unroll
        for (int i = 0; i < 2; ++i) {
            int f = tid + 256 * i;
            int row = f >> 3, k4 = f & 7;
            float4 v = *(const float4*)&h[(size_t)(row0 + row) * NHID + kt + k4 * 4];
            ushort4 hh, ll;
            hh.x = f2bf(v.x); ll.x = f2bf(v.x - bf2f(hh.x));
            hh.y = f2bf(v.y); ll.y = f2bf(v.y - bf2f(hh.y));
            hh.z = f2bf(v.z); ll.z = f2bf(v.z - bf2f(hh.z));
            hh.w = f2bf(v.w); ll.w = f2bf(v.w - bf2f(hh.w));
            *(ushort4*)&Ah[row * ASTR + k4 * 4] = hh;
            *(ushort4*)&Al[row * ASTR + k4 * 4] = ll;
        }
        __syncthreads();
        int ar_ = w * 16 + m16;
        bf16x8 ah  = *(const bf16x8*)&Ah[ar_ * ASTR + kblk * 8];
        bf16x8 alo = *(const bf16x8*)&Al[ar_ * ASTR + kblk * 8];
#pragma unroll
        for (int nr = 0; nr < 3; ++nr) {
            int br = nr * 16 + m16;
            bf16x8 bh = *(const bf16x8*)&Bh[br * OBSTR + kt + kblk * 8];
            bf16x8 bl = *(const bf16x8*)&Bl[br * OBSTR + kt + kblk * 8];
            acc[nr] = __builtin_amdgcn_mfma_f32_16x16x32_bf16(ah,  bh, acc[nr], 0, 0, 0);
            acc[nr] = __builtin_amdgcn_mfma_f32_16x16x32_bf16(ah,  bl, acc[nr], 0, 0, 0);
            acc[nr] = __builtin_amdgcn_mfma_f32_16x16x32_bf16(alo, bh, acc[nr], 0, 0, 0);
        }
        __syncthreads();
    }
#pragma unroll
    for (int nr = 0; nr < 3; ++nr) {
        int col = nr * 16 + m16;
        if (col < NCLASS) {
            float bias = be[col];
#pragma unroll
            for (int r = 0; r < 4; ++r) {
                int row = row0 + w * 16 + kblk * 4 + r;
                out[(size_t)row * NCLASS + col] = (acc[nr][r] + bias) * top[row];
            }
        }
    }
}

extern "C" void kernel_launch(void* const* d_in, const int* in_sizes, int n_in,
                              void* d_out, int out_size, void* d_ws, size_t ws_size,
                              hipStream_t stream) {
    const float* x     = (const float*)d_in[0];
    const int*   ei    = (const int*)d_in[1];
    const float* eattr = (const float*)d_in[2];
    const float* Ws    = (const float*)d_in[3];
    const float* bs    = (const float*)d_in[4];
    const float* attl  = (const float*)d_in[5];
    const float* attr_ = (const float*)d_in[6];
    const float* We    = (const float*)d_in[7];
    const float* be    = (const float*)d_in[8];
    float* out = (float*)d_out;

    char* ws = (char*)d_ws;
    const size_t HB = (size_t)N_NODES * NHID * sizeof(float);   // 32 MB
    float* hA  = (float*)(ws);
    float* hB  = (float*)(ws + HB);
    float* h0  = (float*)(ws + 2 * HB);
    char* sm = ws + 3 * HB;
    float* al       = (float*)(sm);               sm += 131072;
    float* ar       = (float*)(sm);               sm += 131072;
    float* nrm      = (float*)(sm);               sm += 131072;
    float* top      = (float*)(sm);               sm += 131072;
    int*   cnt      = (int*)(sm);                 sm += 131072;
    int*   cur      = (int*)(sm);                 sm += 131072;
    int*   off      = (int*)(sm);                 sm += 262144;  // 32769 ints
    int*   csr_src  = (int*)(sm);                 sm += E_EDGES * 4;
    int*   csr_dst  = (int*)(sm);                 sm += E_EDGES * 4;
    int*   csr_eid  = (int*)(sm);                 sm += E_EDGES * 4;
    float* csr_coef = (float*)(sm);               sm += E_EDGES * 4;
    unsigned short* Whi = (unsigned short*)(sm);  sm += NHID * NFEAT * 2;
    unsigned short* Wlo = (unsigned short*)(sm);  sm += NHID * NFEAT * 2;

    const int* srcp = ei;
    const int* dstp = ei + E_EDGES;

    init_kernel<<<N_NODES / 256, 256, 0, stream>>>(top, cnt, cur);
    count_kernel<<<E_EDGES / 256, 256, 0, stream>>>(dstp, cnt);
    scan_kernel<<<1, 1024, 0, stream>>>(cnt, off);
    scatter_kernel<<<E_EDGES / 256, 256, 0, stream>>>(srcp, dstp, off, cur,
                                                      csr_src, csr_dst, csr_eid);

    wsplit_kernel<<<(NHID * NFEAT / 4) / 256, 256, 0, stream>>>(Ws, Whi, Wlo);
    gemm_direct<<<N_NODES / 64, 256, 0, stream>>>(x, Whi, Wlo, bs, h0);

    float* hin = h0;
    float* hout = hA;
    for (int l = 0; l < 2; ++l) {
        dots_kernel<<<N_NODES / 4, 256, 0, stream>>>(hin, attl + l * NHID, attr_ + l * NHID, al, ar);
        coefcsr_kernel<<<E_EDGES / 256, 256, 0, stream>>>(csr_src, csr_dst, csr_eid, eattr,
                                                          top, al, ar, csr_coef);
        gather_kernel<<<N_NODES / 4, 256, 0, stream>>>(csr_src, off, csr_coef,
                                                       hin, h0, top, hout, nrm);
        int drop_from = (l == 0) ? 256 : 128;
        topk_kernel<<<WLEN, VLEN, 0, stream>>>(nrm, top, drop_from);
        hin = hout;
        hout = (hout == hA) ? hB : hA;
    }

    out_mfma<<<N_NODES / 64, 256, 0, stream>>>(hin, We, be, top, out);
}

// Round 6
// 258.568 us; speedup vs baseline: 1.1336x; 1.1336x over previous
//
#include <hip/hip_runtime.h>
#include <math.h>

#define N_NODES 32768
#define E_EDGES 262144
#define NFEAT   512
#define NHID    256
#define NCLASS  40
#define EPSV    0.1f
#define VLEN    1024
#define WLEN    32

typedef __attribute__((ext_vector_type(8))) short bf16x8;
typedef __attribute__((ext_vector_type(4))) float f32x4;
typedef __attribute__((ext_vector_type(8))) unsigned short us8;

__device__ inline unsigned short f2bf(float f) {
    unsigned int u = __builtin_bit_cast(unsigned int, f);
    return (unsigned short)((u + 0x7FFFu + ((u >> 16) & 1u)) >> 16);
}
__device__ inline float bf2f(unsigned short h) {
    unsigned int u = ((unsigned int)h) << 16;
    return __builtin_bit_cast(float, u);
}

// ---------------- init: top=1, cnt=0, cur=0 ----------------
__global__ void init_kernel(float* __restrict__ top, int* __restrict__ cnt,
                            int* __restrict__ cur) {
    int i = blockIdx.x * 256 + threadIdx.x;
    top[i] = 1.0f;
    cnt[i] = 0;
    cur[i] = 0;
}

// ---------------- count in-degree ----------------
__global__ void count_kernel(const int* __restrict__ dst, int* __restrict__ cnt) {
    int e = blockIdx.x * 256 + threadIdx.x;
    atomicAdd(&cnt[dst[e]], 1);
}

// ---------------- exclusive prefix sum over 32768 counts (1 block) ----------------
__global__ __launch_bounds__(1024) void scan_kernel(const int* __restrict__ cnt,
                                                    int* __restrict__ off) {
    __shared__ int part[1024];
    int t = threadIdx.x;
    int base = t * 32;
    int local[32];
    int s = 0;
#pragma unroll
    for (int i = 0; i < 32; ++i) { local[i] = s; s += cnt[base + i]; }
    part[t] = s;
    __syncthreads();
    for (int d = 1; d < 1024; d <<= 1) {
        int v = (t >= d) ? part[t - d] : 0;
        __syncthreads();
        part[t] += v;
        __syncthreads();
    }
    int prev = (t == 0) ? 0 : part[t - 1];
#pragma unroll
    for (int i = 0; i < 32; ++i) off[base + i] = prev + local[i];
    if (t == 1023) off[N_NODES] = prev + s;
}

// ---------------- scatter edges into CSR slots (store src, dst, w) ----------------
__global__ void scatter_kernel(const int* __restrict__ src, const int* __restrict__ dst,
                               const float* __restrict__ eattr,
                               const int* __restrict__ off, int* __restrict__ cur,
                               int* __restrict__ csr_src, int* __restrict__ csr_dst,
                               float* __restrict__ csr_w) {
    int e = blockIdx.x * 256 + threadIdx.x;
    int d = dst[e];
    int p = atomicAdd(&cur[d], 1);
    int k = off[d] + p;
    csr_src[k] = src[e];
    csr_dst[k] = d;
    csr_w[k]   = eattr[e];
}

// ---------------- split Ws into bf16 hi/lo (once, RNE) ----------------
__global__ void wsplit_kernel(const float* __restrict__ Ws,
                              unsigned short* __restrict__ Whi,
                              unsigned short* __restrict__ Wlo) {
    int i = blockIdx.x * 256 + threadIdx.x;   // float4 index
    float4 v = ((const float4*)Ws)[i];
    ushort4 hh, ll;
    hh.x = f2bf(v.x); ll.x = f2bf(v.x - bf2f(hh.x));
    hh.y = f2bf(v.y); ll.y = f2bf(v.y - bf2f(hh.y));
    hh.z = f2bf(v.z); ll.z = f2bf(v.z - bf2f(hh.z));
    hh.w = f2bf(v.w); ll.w = f2bf(v.w - bf2f(hh.w));
    ((ushort4*)Whi)[i] = hh;
    ((ushort4*)Wlo)[i] = ll;
}

// ---------------- h0 = relu(x @ Ws^T + b) via split-bf16 MFMA ----------------
// BM=64, BN=128, BK=32. grid=1024 -> 4 blocks/CU. 4 waves; wave w owns cols w*32..+32.
#define ASTR 40
#define BSTR 40
__global__ __launch_bounds__(256) void gemm_mfma(
        const float* __restrict__ x, const unsigned short* __restrict__ Whi,
        const unsigned short* __restrict__ Wlo, const float* __restrict__ b,
        float* __restrict__ h0) {
    __shared__ unsigned short Ah[64 * ASTR];
    __shared__ unsigned short Al[64 * ASTR];
    __shared__ unsigned short Bh[128 * BSTR];
    __shared__ unsigned short Bl[128 * BSTR];
    int tid  = threadIdx.x;
    int w    = tid >> 6;
    int lane = tid & 63;
    int m16  = lane & 15;
    int kblk = lane >> 4;
    int row0 = (blockIdx.x >> 1) * 64;
    int col0 = (blockIdx.x & 1) * 128;

    f32x4 acc[4][2];
#pragma unroll
    for (int mr = 0; mr < 4; ++mr)
#pragma unroll
        for (int nr = 0; nr < 2; ++nr)
#pragma unroll
            for (int e = 0; e < 4; ++e) acc[mr][nr][e] = 0.f;

    for (int kt = 0; kt < NFEAT; kt += 32) {
        // stage A: 64x32 fp32 -> bf16 hi/lo (512 float4, 2/thread)
#pragma unroll
        for (int i = 0; i < 2; ++i) {
            int f = tid + 256 * i;
            int row = f >> 3, k4 = f & 7;
            float4 v = *(const float4*)&x[(size_t)(row0 + row) * NFEAT + kt + k4 * 4];
            ushort4 hh, ll;
            hh.x = f2bf(v.x); ll.x = f2bf(v.x - bf2f(hh.x));
            hh.y = f2bf(v.y); ll.y = f2bf(v.y - bf2f(hh.y));
            hh.z = f2bf(v.z); ll.z = f2bf(v.z - bf2f(hh.z));
            hh.w = f2bf(v.w); ll.w = f2bf(v.w - bf2f(hh.w));
            *(ushort4*)&Ah[row * ASTR + k4 * 4] = hh;
            *(ushort4*)&Al[row * ASTR + k4 * 4] = ll;
        }
        // stage B: 128x32 bf16 hi/lo (512 us8 per buffer, 2/thread each)
#pragma unroll
        for (int i = 0; i < 2; ++i) {
            int c = tid + 256 * i;
            int row = c >> 2, k8 = c & 3;
            us8 vh = *(const us8*)&Whi[(size_t)(col0 + row) * NFEAT + kt + k8 * 8];
            us8 vl = *(const us8*)&Wlo[(size_t)(col0 + row) * NFEAT + kt + k8 * 8];
            *(us8*)&Bh[row * BSTR + k8 * 8] = vh;
            *(us8*)&Bl[row * BSTR + k8 * 8] = vl;
        }
        __syncthreads();

        bf16x8 bh[2], bl[2];
#pragma unroll
        for (int nr = 0; nr < 2; ++nr) {
            int r = w * 32 + nr * 16 + m16;
            bh[nr] = *(const bf16x8*)&Bh[r * BSTR + kblk * 8];
            bl[nr] = *(const bf16x8*)&Bl[r * BSTR + kblk * 8];
        }
#pragma unroll
        for (int mr = 0; mr < 4; ++mr) {
            int r = mr * 16 + m16;
            bf16x8 ah  = *(const bf16x8*)&Ah[r * ASTR + kblk * 8];
            bf16x8 alo = *(const bf16x8*)&Al[r * ASTR + kblk * 8];
#pragma unroll
            for (int nr = 0; nr < 2; ++nr) {
                acc[mr][nr] = __builtin_amdgcn_mfma_f32_16x16x32_bf16(ah,  bh[nr], acc[mr][nr], 0, 0, 0);
                acc[mr][nr] = __builtin_amdgcn_mfma_f32_16x16x32_bf16(ah,  bl[nr], acc[mr][nr], 0, 0, 0);
                acc[mr][nr] = __builtin_amdgcn_mfma_f32_16x16x32_bf16(alo, bh[nr], acc[mr][nr], 0, 0, 0);
            }
        }
        __syncthreads();
    }
#pragma unroll
    for (int nr = 0; nr < 2; ++nr) {
        int col = col0 + w * 32 + nr * 16 + m16;
        float bias = b[col];
#pragma unroll
        for (int mr = 0; mr < 4; ++mr) {
#pragma unroll
            for (int r = 0; r < 4; ++r) {
                int row = row0 + mr * 16 + kblk * 4 + r;
                float v = acc[mr][nr][r] + bias;
                h0[(size_t)row * NHID + col] = v > 0.f ? v : 0.f;
            }
        }
    }
}

// ---------------- al[i] = h[i]·attl, ar[i] = h[i]·attr (layer 0 only) ----------------
__global__ __launch_bounds__(256) void dots_kernel(
        const float* __restrict__ h, const float* __restrict__ attl,
        const float* __restrict__ attr_, float* __restrict__ al, float* __restrict__ ar) {
    int node = blockIdx.x * 4 + (threadIdx.x >> 6);
    int lane = threadIdx.x & 63;
    float4 hv = *(const float4*)&h[(size_t)node * NHID + lane * 4];
    float4 lv = *(const float4*)&attl[lane * 4];
    float4 rv = *(const float4*)&attr_[lane * 4];
    float sl = hv.x * lv.x + hv.y * lv.y + hv.z * lv.z + hv.w * lv.w;
    float sr = hv.x * rv.x + hv.y * rv.y + hv.z * rv.z + hv.w * rv.w;
#pragma unroll
    for (int off = 32; off; off >>= 1) {
        sl += __shfl_down(sl, off);
        sr += __shfl_down(sr, off);
    }
    if (lane == 0) { al[node] = sl; ar[node] = sr; }
}

// ---------------- per-slot coefficient, CSR order (coalesced) ----------------
__global__ void coefcsr_kernel(const int* __restrict__ csr_src, const int* __restrict__ csr_dst,
                               const float* __restrict__ csr_w,
                               const float* __restrict__ top, const float* __restrict__ al,
                               const float* __restrict__ ar, float* __restrict__ csr_coef) {
    int k = blockIdx.x * 256 + threadIdx.x;
    int s = csr_src[k], d = csr_dst[k];
    float w = csr_w[k] * top[s] * top[d];
    csr_coef[k] = (w == 0.f) ? 0.f : tanhf(al[s] + ar[d]) * w;
}

// ---------------- gather: h_out[d] = sum coef*h_in[src] + eps*h0[d]; nrm; fused next-layer dots ----------------
__global__ __launch_bounds__(256) void gather_kernel(
        const int* __restrict__ csr_src, const int* __restrict__ off,
        const float* __restrict__ csr_coef, const float* __restrict__ h_in,
        const float* __restrict__ h0, const float* __restrict__ top,
        float* __restrict__ h_out, float* __restrict__ nrm,
        const float* __restrict__ attl_next, const float* __restrict__ attr_next,
        float* __restrict__ al, float* __restrict__ ar, int want_dots) {
    int node = blockIdx.x * 4 + (threadIdx.x >> 6);
    int lane = threadIdx.x & 63;
    size_t base = (size_t)node * NHID + lane * 4;
    float t = top[node];
    if (t == 0.f) {
        *(float4*)&h_out[base] = make_float4(0.f, 0.f, 0.f, 0.f);
        if (lane == 0) {
            nrm[node] = 0.f;
            if (want_dots) { al[node] = 0.f; ar[node] = 0.f; }
        }
        return;
    }
    int k0 = off[node], k1 = off[node + 1];
    float4 acc = make_float4(0.f, 0.f, 0.f, 0.f);
    int k = k0;
    for (; k + 3 < k1; k += 4) {
        float c0 = csr_coef[k],     c1 = csr_coef[k + 1];
        float c2 = csr_coef[k + 2], c3 = csr_coef[k + 3];
        int   s0 = csr_src[k],      s1 = csr_src[k + 1];
        int   s2 = csr_src[k + 2],  s3 = csr_src[k + 3];
        if (c0 != 0.f && c1 != 0.f && c2 != 0.f && c3 != 0.f) {
            float4 v0 = *(const float4*)&h_in[(size_t)s0 * NHID + lane * 4];
            float4 v1 = *(const float4*)&h_in[(size_t)s1 * NHID + lane * 4];
            float4 v2 = *(const float4*)&h_in[(size_t)s2 * NHID + lane * 4];
            float4 v3 = *(const float4*)&h_in[(size_t)s3 * NHID + lane * 4];
            acc.x += c0 * v0.x + c1 * v1.x + c2 * v2.x + c3 * v3.x;
            acc.y += c0 * v0.y + c1 * v1.y + c2 * v2.y + c3 * v3.y;
            acc.z += c0 * v0.z + c1 * v1.z + c2 * v2.z + c3 * v3.z;
            acc.w += c0 * v0.w + c1 * v1.w + c2 * v2.w + c3 * v3.w;
        } else {
            if (c0 != 0.f) { float4 v = *(const float4*)&h_in[(size_t)s0 * NHID + lane * 4];
                acc.x += c0 * v.x; acc.y += c0 * v.y; acc.z += c0 * v.z; acc.w += c0 * v.w; }
            if (c1 != 0.f) { float4 v = *(const float4*)&h_in[(size_t)s1 * NHID + lane * 4];
                acc.x += c1 * v.x; acc.y += c1 * v.y; acc.z += c1 * v.z; acc.w += c1 * v.w; }
            if (c2 != 0.f) { float4 v = *(const float4*)&h_in[(size_t)s2 * NHID + lane * 4];
                acc.x += c2 * v.x; acc.y += c2 * v.y; acc.z += c2 * v.z; acc.w += c2 * v.w; }
            if (c3 != 0.f) { float4 v = *(const float4*)&h_in[(size_t)s3 * NHID + lane * 4];
                acc.x += c3 * v.x; acc.y += c3 * v.y; acc.z += c3 * v.z; acc.w += c3 * v.w; }
        }
    }
    for (; k < k1; ++k) {
        float c = csr_coef[k];
        if (c != 0.f) {
            int s = csr_src[k];
            float4 v = *(const float4*)&h_in[(size_t)s * NHID + lane * 4];
            acc.x += c * v.x; acc.y += c * v.y; acc.z += c * v.z; acc.w += c * v.w;
        }
    }
    float4 z = *(const float4*)&h0[base];
    float4 v;
    v.x = acc.x + EPSV * z.x;
    v.y = acc.y + EPSV * z.y;
    v.z = acc.z + EPSV * z.z;
    v.w = acc.w + EPSV * z.w;
    *(float4*)&h_out[base] = v;
    float ss = v.x * v.x + v.y * v.y + v.z * v.z + v.w * v.w;
    if (want_dots) {
        float4 lv = *(const float4*)&attl_next[lane * 4];
        float4 rv = *(const float4*)&attr_next[lane * 4];
        float sl = v.x * lv.x + v.y * lv.y + v.z * lv.z + v.w * lv.w;
        float sr = v.x * rv.x + v.y * rv.y + v.z * rv.z + v.w * rv.w;
#pragma unroll
        for (int o = 32; o; o >>= 1) {
            ss += __shfl_down(ss, o);
            sl += __shfl_down(sl, o);
            sr += __shfl_down(sr, o);
        }
        if (lane == 0) { nrm[node] = sqrtf(ss); al[node] = sl; ar[node] = sr; }
    } else {
#pragma unroll
        for (int o = 32; o; o >>= 1) ss += __shfl_down(ss, o);
        if (lane == 0) nrm[node] = sqrtf(ss);
    }
}

// ---------------- per-column stable top-k ----------------
__global__ __launch_bounds__(1024) void topk_kernel(
        const float* __restrict__ nrm, float* __restrict__ top, int drop_from) {
    __shared__ float s[VLEN];
    int c = blockIdx.x;
    int r = threadIdx.x;
    float v = nrm[r * WLEN + c];
    s[r] = v;
    __syncthreads();
    int cnt = 0;
    for (int r2 = 0; r2 < VLEN; ++r2) {
        float v2 = s[r2];
        cnt += (v2 > v) || (v2 == v && r2 < r);
    }
    if (cnt >= drop_from) top[r * WLEN + c] = 0.f;
}

// ---------------- out = (h @ We^T + be) * top via split-bf16 MFMA ----------------
#define OBSTR 264
__global__ __launch_bounds__(256) void out_mfma(
        const float* __restrict__ h, const float* __restrict__ We,
        const float* __restrict__ be, const float* __restrict__ top,
        float* __restrict__ out) {
    __shared__ unsigned short Bh[48 * OBSTR];
    __shared__ unsigned short Bl[48 * OBSTR];
    __shared__ unsigned short Ah[64 * ASTR];
    __shared__ unsigned short Al[64 * ASTR];
    int tid  = threadIdx.x;
    int w    = tid >> 6;
    int lane = tid & 63;
    int m16  = lane & 15;
    int kblk = lane >> 4;
    int row0 = blockIdx.x * 64;

    for (int i = tid; i < 48 * 64; i += 256) {
        int r = i >> 6, k4 = i & 63;
        float4 v = (r < NCLASS) ? *(const float4*)&We[r * NHID + k4 * 4]
                                : make_float4(0.f, 0.f, 0.f, 0.f);
        ushort4 hh, ll;
        hh.x = f2bf(v.x); ll.x = f2bf(v.x - bf2f(hh.x));
        hh.y = f2bf(v.y); ll.y = f2bf(v.y - bf2f(hh.y));
        hh.z = f2bf(v.z); ll.z = f2bf(v.z - bf2f(hh.z));
        hh.w = f2bf(v.w); ll.w = f2bf(v.w - bf2f(hh.w));
        *(ushort4*)&Bh[r * OBSTR + k4 * 4] = hh;
        *(ushort4*)&Bl[r * OBSTR + k4 * 4] = ll;
    }

    f32x4 acc[3];
#pragma unroll
    for (int nr = 0; nr < 3; ++nr)
#pragma unroll
        for (int e = 0; e < 4; ++e) acc[nr][e] = 0.f;

    for (int kt = 0; kt < NHID; kt += 32) {
#pragma unroll
        for (int i = 0; i < 2; ++i) {
            int f = tid + 256 * i;
            int row = f >> 3, k4 = f & 7;
            float4 v = *(const float4*)&h[(size_t)(row0 + row) * NHID + kt + k4 * 4];
            ushort4 hh, ll;
            hh.x = f2bf(v.x); ll.x = f2bf(v.x - bf2f(hh.x));
            hh.y = f2bf(v.y); ll.y = f2bf(v.y - bf2f(hh.y));
            hh.z = f2bf(v.z); ll.z = f2bf(v.z - bf2f(hh.z));
            hh.w = f2bf(v.w); ll.w = f2bf(v.w - bf2f(hh.w));
            *(ushort4*)&Ah[row * ASTR + k4 * 4] = hh;
            *(ushort4*)&Al[row * ASTR + k4 * 4] = ll;
        }
        __syncthreads();
        int ar_ = w * 16 + m16;
        bf16x8 ah  = *(const bf16x8*)&Ah[ar_ * ASTR + kblk * 8];
        bf16x8 alo = *(const bf16x8*)&Al[ar_ * ASTR + kblk * 8];
#pragma unroll
        for (int nr = 0; nr < 3; ++nr) {
            int br = nr * 16 + m16;
            bf16x8 bh = *(const bf16x8*)&Bh[br * OBSTR + kt + kblk * 8];
            bf16x8 bl = *(const bf16x8*)&Bl[br * OBSTR + kt + kblk * 8];
            acc[nr] = __builtin_amdgcn_mfma_f32_16x16x32_bf16(ah,  bh, acc[nr], 0, 0, 0);
            acc[nr] = __builtin_amdgcn_mfma_f32_16x16x32_bf16(ah,  bl, acc[nr], 0, 0, 0);
            acc[nr] = __builtin_amdgcn_mfma_f32_16x16x32_bf16(alo, bh, acc[nr], 0, 0, 0);
        }
        __syncthreads();
    }
#pragma unroll
    for (int nr = 0; nr < 3; ++nr) {
        int col = nr * 16 + m16;
        if (col < NCLASS) {
            float bias = be[col];
#pragma unroll
            for (int r = 0; r < 4; ++r) {
                int row = row0 + w * 16 + kblk * 4 + r;
                out[(size_t)row * NCLASS + col] = (acc[nr][r] + bias) * top[row];
            }
        }
    }
}

extern "C" void kernel_launch(void* const* d_in, const int* in_sizes, int n_in,
                              void* d_out, int out_size, void* d_ws, size_t ws_size,
                              hipStream_t stream) {
    const float* x     = (const float*)d_in[0];
    const int*   ei    = (const int*)d_in[1];
    const float* eattr = (const float*)d_in[2];
    const float* Ws    = (const float*)d_in[3];
    const float* bs    = (const float*)d_in[4];
    const float* attl  = (const float*)d_in[5];
    const float* attr_ = (const float*)d_in[6];
    const float* We    = (const float*)d_in[7];
    const float* be    = (const float*)d_in[8];
    float* out = (float*)d_out;

    char* ws = (char*)d_ws;
    const size_t HB = (size_t)N_NODES * NHID * sizeof(float);   // 32 MB
    float* hA  = (float*)(ws);
    float* hB  = (float*)(ws + HB);
    float* h0  = (float*)(ws + 2 * HB);
    char* sm = ws + 3 * HB;
    float* al       = (float*)(sm);               sm += 131072;
    float* ar       = (float*)(sm);               sm += 131072;
    float* nrm      = (float*)(sm);               sm += 131072;
    float* top      = (float*)(sm);               sm += 131072;
    int*   cnt      = (int*)(sm);                 sm += 131072;
    int*   cur      = (int*)(sm);                 sm += 131072;
    int*   off      = (int*)(sm);                 sm += 262144;  // 32769 ints
    int*   csr_src  = (int*)(sm);                 sm += E_EDGES * 4;
    int*   csr_dst  = (int*)(sm);                 sm += E_EDGES * 4;
    float* csr_w    = (float*)(sm);               sm += E_EDGES * 4;
    float* csr_coef = (float*)(sm);               sm += E_EDGES * 4;
    unsigned short* Whi = (unsigned short*)(sm);  sm += NHID * NFEAT * 2;
    unsigned short* Wlo = (unsigned short*)(sm);  sm += NHID * NFEAT * 2;

    const int* srcp = ei;
    const int* dstp = ei + E_EDGES;

    init_kernel<<<N_NODES / 256, 256, 0, stream>>>(top, cnt, cur);
    count_kernel<<<E_EDGES / 256, 256, 0, stream>>>(dstp, cnt);
    scan_kernel<<<1, 1024, 0, stream>>>(cnt, off);
    scatter_kernel<<<E_EDGES / 256, 256, 0, stream>>>(srcp, dstp, eattr, off, cur,
                                                      csr_src, csr_dst, csr_w);

    wsplit_kernel<<<(NHID * NFEAT / 4) / 256, 256, 0, stream>>>(Ws, Whi, Wlo);
    gemm_mfma<<<(N_NODES / 64) * 2, 256, 0, stream>>>(x, Whi, Wlo, bs, h0);

    // layer-0 attention dots on h0
    dots_kernel<<<N_NODES / 4, 256, 0, stream>>>(h0, attl, attr_, al, ar);

    float* hin = h0;
    float* hout = hA;
    for (int l = 0; l < 2; ++l) {
        coefcsr_kernel<<<E_EDGES / 256, 256, 0, stream>>>(csr_src, csr_dst, csr_w,
                                                          top, al, ar, csr_coef);
        int want_dots = (l == 0) ? 1 : 0;
        gather_kernel<<<N_NODES / 4, 256, 0, stream>>>(csr_src, off, csr_coef,
                                                       hin, h0, top, hout, nrm,
                                                       attl + NHID, attr_ + NHID,
                                                       al, ar, want_dots);
        int drop_from = (l == 0) ? 256 : 128;
        topk_kernel<<<WLEN, VLEN, 0, stream>>>(nrm, top, drop_from);
        hin = hout;
        hout = (hout == hA) ? hB : hA;
    }

    out_mfma<<<N_NODES / 64, 256, 0, stream>>>(hin, We, be, top, out);
}

// Round 7
// 252.516 us; speedup vs baseline: 1.1607x; 1.0240x over previous
//
#include <hip/hip_runtime.h>
#include <math.h>

#define N_NODES 32768
#define E_EDGES 262144
#define NFEAT   512
#define NHID    256
#define NCLASS  40
#define EPSV    0.1f
#define VLEN    1024
#define WLEN    32

typedef __attribute__((ext_vector_type(8)))  short bf16x8;
typedef __attribute__((ext_vector_type(4)))  float f32x4;
typedef __attribute__((ext_vector_type(16))) float f32x16;
typedef __attribute__((ext_vector_type(4)))  int   i32x4;
typedef __attribute__((ext_vector_type(8)))  unsigned short us8;

__device__ inline unsigned short f2bf(float f) {
    unsigned int u = __builtin_bit_cast(unsigned int, f);
    return (unsigned short)((u + 0x7FFFu + ((u >> 16) & 1u)) >> 16);
}
__device__ inline float bf2f(unsigned short h) {
    unsigned int u = ((unsigned int)h) << 16;
    return __builtin_bit_cast(float, u);
}

// truncation split of a pair of fp32 into packed bf16 hi and lo dwords.
__device__ inline void split_pair(float a, float b, unsigned& hi, unsigned& lo) {
    unsigned ua = __builtin_bit_cast(unsigned, a);
    unsigned ub = __builtin_bit_cast(unsigned, b);
    unsigned ha = ua & 0xFFFF0000u, hb = ub & 0xFFFF0000u;
    hi = (ha >> 16) | hb;
    float la = a - __builtin_bit_cast(float, ha);
    float lb = b - __builtin_bit_cast(float, hb);
    unsigned ula = __builtin_bit_cast(unsigned, la);
    unsigned ulb = __builtin_bit_cast(unsigned, lb);
    lo = (ula >> 16) | (ulb & 0xFFFF0000u);
}

// async global->LDS, 16B per lane. LDS dest = wave-uniform base + lane*16.
__device__ __forceinline__ void gload16(const void* g, void* l) {
    __builtin_amdgcn_global_load_lds(
        (const __attribute__((address_space(1))) unsigned int*)g,
        (__attribute__((address_space(3))) unsigned int*)l,
        16, 0, 0);
}

// ---------------- init: top=1, cnt=0, cur=0 ----------------
__global__ void init_kernel(float* __restrict__ top, int* __restrict__ cnt,
                            int* __restrict__ cur) {
    int i = blockIdx.x * 256 + threadIdx.x;
    top[i] = 1.0f;
    cnt[i] = 0;
    cur[i] = 0;
}

// ---------------- count in-degree ----------------
__global__ void count_kernel(const int* __restrict__ dst, int* __restrict__ cnt) {
    int e = blockIdx.x * 256 + threadIdx.x;
    atomicAdd(&cnt[dst[e]], 1);
}

// ---------------- exclusive prefix sum over 32768 counts (1 block) ----------------
__global__ __launch_bounds__(1024) void scan_kernel(const int* __restrict__ cnt,
                                                    int* __restrict__ off) {
    __shared__ int part[1024];
    int t = threadIdx.x;
    int base = t * 32;
    int local[32];
    int s = 0;
#pragma unroll
    for (int i = 0; i < 32; ++i) { local[i] = s; s += cnt[base + i]; }
    part[t] = s;
    __syncthreads();
    for (int d = 1; d < 1024; d <<= 1) {
        int v = (t >= d) ? part[t - d] : 0;
        __syncthreads();
        part[t] += v;
        __syncthreads();
    }
    int prev = (t == 0) ? 0 : part[t - 1];
#pragma unroll
    for (int i = 0; i < 32; ++i) off[base + i] = prev + local[i];
    if (t == 1023) off[N_NODES] = prev + s;
}

// ---------------- scatter edges into CSR slots (store src, dst, w) ----------------
__global__ void scatter_kernel(const int* __restrict__ src, const int* __restrict__ dst,
                               const float* __restrict__ eattr,
                               const int* __restrict__ off, int* __restrict__ cur,
                               int* __restrict__ csr_src, int* __restrict__ csr_dst,
                               float* __restrict__ csr_w) {
    int e = blockIdx.x * 256 + threadIdx.x;
    int d = dst[e];
    int p = atomicAdd(&cur[d], 1);
    int k = off[d] + p;
    csr_src[k] = src[e];
    csr_dst[k] = d;
    csr_w[k]   = eattr[e];
}

// ---------------- split Ws into bf16 hi/lo (once, RNE) ----------------
__global__ void wsplit_kernel(const float* __restrict__ Ws,
                              unsigned short* __restrict__ Whi,
                              unsigned short* __restrict__ Wlo) {
    int i = blockIdx.x * 256 + threadIdx.x;   // float4 index
    float4 v = ((const float4*)Ws)[i];
    ushort4 hh, ll;
    hh.x = f2bf(v.x); ll.x = f2bf(v.x - bf2f(hh.x));
    hh.y = f2bf(v.y); ll.y = f2bf(v.y - bf2f(hh.y));
    hh.z = f2bf(v.z); ll.z = f2bf(v.z - bf2f(hh.z));
    hh.w = f2bf(v.w); ll.w = f2bf(v.w - bf2f(hh.w));
    ((ushort4*)Whi)[i] = hh;
    ((ushort4*)Wlo)[i] = ll;
}

// ---------------- h0 = relu(x @ Ws^T + b), 32x32x16 MFMA + global_load_lds ----------------
// BM=BN=128, BK=32; 4 waves as 2x2, each owning 64x64 (2x2 tiles of 32x32).
// A staged as fp32 (converted to split-bf16 at fragment read), B staged as bf16 hi/lo.
// LDS linear + involution swizzle: pre-swizzled global source, XOR on read (rule #21).
//   A (128B rows): byte off ^= (row&7)<<4 ;  B (64B rows): byte off ^= ((col>>1)&3)<<4
__global__ __launch_bounds__(256, 2) void gemm_mfma32(
        const float* __restrict__ x, const unsigned short* __restrict__ Whi,
        const unsigned short* __restrict__ Wlo, const float* __restrict__ b,
        float* __restrict__ h0) {
    __shared__ float          As[2][128 * 32];    // 16 KB each
    __shared__ unsigned short Bhs[2][128 * 32];   // 8 KB each
    __shared__ unsigned short Bls[2][128 * 32];   // 8 KB each

    int tid  = threadIdx.x;
    int w    = tid >> 6;
    int lane = tid & 63;
    int l31  = lane & 31;
    int khalf = lane >> 5;
    int wr = w >> 1, wc = w & 1;

    // bijective XCD swizzle (512 % 8 == 0): consecutive tiles share an XCD L2
    int wg = (blockIdx.x & 7) * 64 + (blockIdx.x >> 3);
    int row0 = (wg >> 1) * 128;
    int col0 = (wg & 1) * 128;

    f32x16 acc[2][2];
#pragma unroll
    for (int mr = 0; mr < 2; ++mr)
#pragma unroll
        for (int nr = 0; nr < 2; ++nr)
#pragma unroll
            for (int e = 0; e < 16; ++e) acc[mr][nr][e] = 0.f;

    // ---- staging: 8 gload16 per wave per K-tile (4 A-fp32, 2 Bh, 2 Bl) ----
    auto stage = [&](int kt, int buf) {
#pragma unroll
        for (int i = 0; i < 4; ++i) {
            int d    = (w * 4 + i) * 1024 + lane * 16;  // byte idx in 16KB A tile
            int row  = d >> 7;                          // 128B per row
            int off  = d & 127;
            int loff = off ^ ((row & 7) << 4);          // inverse swizzle on source
            const float* src = &x[(size_t)(row0 + row) * NFEAT + kt * 32 + (loff >> 2)];
            gload16(src, &As[buf][(w * 4 + i) * 256]);
        }
#pragma unroll
        for (int i = 0; i < 2; ++i) {
            int d     = (w * 2 + i) * 1024 + lane * 16; // byte idx in 8KB B tile
            int wrow  = d >> 6;                         // 64B per row
            int slot  = (d >> 4) & 3;
            int lslot = slot ^ ((wrow >> 1) & 3);
            size_t so = (size_t)(col0 + wrow) * NFEAT + kt * 32 + lslot * 8;
            gload16(&Whi[so], &Bhs[buf][(w * 2 + i) * 512]);
            gload16(&Wlo[so], &Bls[buf][(w * 2 + i) * 512]);
        }
    };

    stage(0, 0);
    __syncthreads();   // compiler drains vmcnt before s_barrier

    for (int kt = 0; kt < NFEAT / 32; ++kt) {
        int cur = kt & 1;
        if (kt + 1 < NFEAT / 32) stage(kt + 1, cur ^ 1);   // prefetch overlaps compute

        const float*          Ab  = As[cur];
        const unsigned short* Bhb = Bhs[cur];
        const unsigned short* Blb = Bls[cur];

#pragma unroll
        for (int s = 0; s < 2; ++s) {          // two K=16 steps per K-tile
            bf16x8 ah[2], al[2];
#pragma unroll
            for (int mr = 0; mr < 2; ++mr) {
                int rt = wr * 64 + mr * 32 + l31;
                const char* rowp = (const char*)(Ab + rt * 32);
                int lo0 = s * 64 + khalf * 32;
                int sw  = (rt & 7) << 4;
                f32x4 va = *(const f32x4*)(rowp + (lo0 ^ sw));
                f32x4 vb = *(const f32x4*)(rowp + ((lo0 + 16) ^ sw));
                unsigned h01, h23, h45, h67, l01, l23, l45, l67;
                split_pair(va[0], va[1], h01, l01);
                split_pair(va[2], va[3], h23, l23);
                split_pair(vb[0], vb[1], h45, l45);
                split_pair(vb[2], vb[3], h67, l67);
                i32x4 hv = {(int)h01, (int)h23, (int)h45, (int)h67};
                i32x4 lv = {(int)l01, (int)l23, (int)l45, (int)l67};
                ah[mr] = __builtin_bit_cast(bf16x8, hv);
                al[mr] = __builtin_bit_cast(bf16x8, lv);
            }
            bf16x8 bh[2], bl[2];
#pragma unroll
            for (int nr = 0; nr < 2; ++nr) {
                int ct = wc * 64 + nr * 32 + l31;
                int lb = s * 32 + khalf * 16;
                int ob = lb ^ (((ct >> 1) & 3) << 4);
                bh[nr] = *(const bf16x8*)((const char*)(Bhb + ct * 32) + ob);
                bl[nr] = *(const bf16x8*)((const char*)(Blb + ct * 32) + ob);
            }
#pragma unroll
            for (int mr = 0; mr < 2; ++mr)
#pragma unroll
                for (int nr = 0; nr < 2; ++nr) {
                    acc[mr][nr] = __builtin_amdgcn_mfma_f32_32x32x16_bf16(ah[mr], bh[nr], acc[mr][nr], 0, 0, 0);
                    acc[mr][nr] = __builtin_amdgcn_mfma_f32_32x32x16_bf16(ah[mr], bl[nr], acc[mr][nr], 0, 0, 0);
                    acc[mr][nr] = __builtin_amdgcn_mfma_f32_32x32x16_bf16(al[mr], bh[nr], acc[mr][nr], 0, 0, 0);
                }
        }
        __syncthreads();   // drains vmcnt (prefetch DMA) + protects buffer swap
    }

    // epilogue: D col=lane&31, row=(reg&3)+8*(reg>>2)+4*(lane>>5)  [m74/m101]
#pragma unroll
    for (int nr = 0; nr < 2; ++nr) {
        int col = col0 + wc * 64 + nr * 32 + l31;
        float bias = b[col];
#pragma unroll
        for (int mr = 0; mr < 2; ++mr) {
#pragma unroll
            for (int r = 0; r < 16; ++r) {
                int rowt = (r & 3) + 8 * (r >> 2) + 4 * khalf;
                int row = row0 + wr * 64 + mr * 32 + rowt;
                float v = acc[mr][nr][r] + bias;
                h0[(size_t)row * NHID + col] = v > 0.f ? v : 0.f;
            }
        }
    }
}

// ---------------- al[i] = h[i]·attl, ar[i] = h[i]·attr (layer 0 only) ----------------
__global__ __launch_bounds__(256) void dots_kernel(
        const float* __restrict__ h, const float* __restrict__ attl,
        const float* __restrict__ attr_, float* __restrict__ al, float* __restrict__ ar) {
    int node = blockIdx.x * 4 + (threadIdx.x >> 6);
    int lane = threadIdx.x & 63;
    float4 hv = *(const float4*)&h[(size_t)node * NHID + lane * 4];
    float4 lv = *(const float4*)&attl[lane * 4];
    float4 rv = *(const float4*)&attr_[lane * 4];
    float sl = hv.x * lv.x + hv.y * lv.y + hv.z * lv.z + hv.w * lv.w;
    float sr = hv.x * rv.x + hv.y * rv.y + hv.z * rv.z + hv.w * rv.w;
#pragma unroll
    for (int off = 32; off; off >>= 1) {
        sl += __shfl_down(sl, off);
        sr += __shfl_down(sr, off);
    }
    if (lane == 0) { al[node] = sl; ar[node] = sr; }
}

// ---------------- per-slot coefficient, CSR order (coalesced) ----------------
__global__ void coefcsr_kernel(const int* __restrict__ csr_src, const int* __restrict__ csr_dst,
                               const float* __restrict__ csr_w,
                               const float* __restrict__ top, const float* __restrict__ al,
                               const float* __restrict__ ar, float* __restrict__ csr_coef) {
    int k = blockIdx.x * 256 + threadIdx.x;
    int s = csr_src[k], d = csr_dst[k];
    float w = csr_w[k] * top[s] * top[d];
    csr_coef[k] = (w == 0.f) ? 0.f : tanhf(al[s] + ar[d]) * w;
}

// ---------------- gather: h_out[d] = sum coef*h_in[src] + eps*h0[d]; nrm; fused next-layer dots ----------------
__global__ __launch_bounds__(256) void gather_kernel(
        const int* __restrict__ csr_src, const int* __restrict__ off,
        const float* __restrict__ csr_coef, const float* __restrict__ h_in,
        const float* __restrict__ h0, const float* __restrict__ top,
        float* __restrict__ h_out, float* __restrict__ nrm,
        const float* __restrict__ attl_next, const float* __restrict__ attr_next,
        float* __restrict__ al, float* __restrict__ ar, int want_dots) {
    int node = blockIdx.x * 4 + (threadIdx.x >> 6);
    int lane = threadIdx.x & 63;
    size_t base = (size_t)node * NHID + lane * 4;
    float t = top[node];
    if (t == 0.f) {
        *(float4*)&h_out[base] = make_float4(0.f, 0.f, 0.f, 0.f);
        if (lane == 0) {
            nrm[node] = 0.f;
            if (want_dots) { al[node] = 0.f; ar[node] = 0.f; }
        }
        return;
    }
    int k0 = off[node], k1 = off[node + 1];
    float4 acc = make_float4(0.f, 0.f, 0.f, 0.f);
    int k = k0;
    for (; k + 3 < k1; k += 4) {
        float c0 = csr_coef[k],     c1 = csr_coef[k + 1];
        float c2 = csr_coef[k + 2], c3 = csr_coef[k + 3];
        int   s0 = csr_src[k],      s1 = csr_src[k + 1];
        int   s2 = csr_src[k + 2],  s3 = csr_src[k + 3];
        if (c0 != 0.f && c1 != 0.f && c2 != 0.f && c3 != 0.f) {
            float4 v0 = *(const float4*)&h_in[(size_t)s0 * NHID + lane * 4];
            float4 v1 = *(const float4*)&h_in[(size_t)s1 * NHID + lane * 4];
            float4 v2 = *(const float4*)&h_in[(size_t)s2 * NHID + lane * 4];
            float4 v3 = *(const float4*)&h_in[(size_t)s3 * NHID + lane * 4];
            acc.x += c0 * v0.x + c1 * v1.x + c2 * v2.x + c3 * v3.x;
            acc.y += c0 * v0.y + c1 * v1.y + c2 * v2.y + c3 * v3.y;
            acc.z += c0 * v0.z + c1 * v1.z + c2 * v2.z + c3 * v3.z;
            acc.w += c0 * v0.w + c1 * v1.w + c2 * v2.w + c3 * v3.w;
        } else {
            if (c0 != 0.f) { float4 v = *(const float4*)&h_in[(size_t)s0 * NHID + lane * 4];
                acc.x += c0 * v.x; acc.y += c0 * v.y; acc.z += c0 * v.z; acc.w += c0 * v.w; }
            if (c1 != 0.f) { float4 v = *(const float4*)&h_in[(size_t)s1 * NHID + lane * 4];
                acc.x += c1 * v.x; acc.y += c1 * v.y; acc.z += c1 * v.z; acc.w += c1 * v.w; }
            if (c2 != 0.f) { float4 v = *(const float4*)&h_in[(size_t)s2 * NHID + lane * 4];
                acc.x += c2 * v.x; acc.y += c2 * v.y; acc.z += c2 * v.z; acc.w += c2 * v.w; }
            if (c3 != 0.f) { float4 v = *(const float4*)&h_in[(size_t)s3 * NHID + lane * 4];
                acc.x += c3 * v.x; acc.y += c3 * v.y; acc.z += c3 * v.z; acc.w += c3 * v.w; }
        }
    }
    for (; k < k1; ++k) {
        float c = csr_coef[k];
        if (c != 0.f) {
            int s = csr_src[k];
            float4 v = *(const float4*)&h_in[(size_t)s * NHID + lane * 4];
            acc.x += c * v.x; acc.y += c * v.y; acc.z += c * v.z; acc.w += c * v.w;
        }
    }
    float4 z = *(const float4*)&h0[base];
    float4 v;
    v.x = acc.x + EPSV * z.x;
    v.y = acc.y + EPSV * z.y;
    v.z = acc.z + EPSV * z.z;
    v.w = acc.w + EPSV * z.w;
    *(float4*)&h_out[base] = v;
    float ss = v.x * v.x + v.y * v.y + v.z * v.z + v.w * v.w;
    if (want_dots) {
        float4 lv = *(const float4*)&attl_next[lane * 4];
        float4 rv = *(const float4*)&attr_next[lane * 4];
        float sl = v.x * lv.x + v.y * lv.y + v.z * lv.z + v.w * lv.w;
        float sr = v.x * rv.x + v.y * rv.y + v.z * rv.z + v.w * rv.w;
#pragma unroll
        for (int o = 32; o; o >>= 1) {
            ss += __shfl_down(ss, o);
            sl += __shfl_down(sl, o);
            sr += __shfl_down(sr, o);
        }
        if (lane == 0) { nrm[node] = sqrtf(ss); al[node] = sl; ar[node] = sr; }
    } else {
#pragma unroll
        for (int o = 32; o; o >>= 1) ss += __shfl_down(ss, o);
        if (lane == 0) nrm[node] = sqrtf(ss);
    }
}

// ---------------- per-column stable top-k ----------------
__global__ __launch_bounds__(1024) void topk_kernel(
        const float* __restrict__ nrm, float* __restrict__ top, int drop_from) {
    __shared__ float s[VLEN];
    int c = blockIdx.x;
    int r = threadIdx.x;
    float v = nrm[r * WLEN + c];
    s[r] = v;
    __syncthreads();
    int cnt = 0;
    for (int r2 = 0; r2 < VLEN; ++r2) {
        float v2 = s[r2];
        cnt += (v2 > v) || (v2 == v && r2 < r);
    }
    if (cnt >= drop_from) top[r * WLEN + c] = 0.f;
}

// ---------------- out = (h @ We^T + be) * top via split-bf16 MFMA ----------------
#define ASTR 40
#define OBSTR 264
__global__ __launch_bounds__(256) void out_mfma(
        const float* __restrict__ h, const float* __restrict__ We,
        const float* __restrict__ be, const float* __restrict__ top,
        float* __restrict__ out) {
    __shared__ unsigned short Bh[48 * OBSTR];
    __shared__ unsigned short Bl[48 * OBSTR];
    __shared__ unsigned short Ah[64 * ASTR];
    __shared__ unsigned short Al[64 * ASTR];
    int tid  = threadIdx.x;
    int w    = tid >> 6;
    int lane = tid & 63;
    int m16  = lane & 15;
    int kblk = lane >> 4;
    int row0 = blockIdx.x * 64;

    for (int i = tid; i < 48 * 64; i += 256) {
        int r = i >> 6, k4 = i & 63;
        float4 v = (r < NCLASS) ? *(const float4*)&We[r * NHID + k4 * 4]
                                : make_float4(0.f, 0.f, 0.f, 0.f);
        ushort4 hh, ll;
        hh.x = f2bf(v.x); ll.x = f2bf(v.x - bf2f(hh.x));
        hh.y = f2bf(v.y); ll.y = f2bf(v.y - bf2f(hh.y));
        hh.z = f2bf(v.z); ll.z = f2bf(v.z - bf2f(hh.z));
        hh.w = f2bf(v.w); ll.w = f2bf(v.w - bf2f(hh.w));
        *(ushort4*)&Bh[r * OBSTR + k4 * 4] = hh;
        *(ushort4*)&Bl[r * OBSTR + k4 * 4] = ll;
    }

    f32x4 acc[3];
#pragma unroll
    for (int nr = 0; nr < 3; ++nr)
#pragma unroll
        for (int e = 0; e < 4; ++e) acc[nr][e] = 0.f;

    for (int kt = 0; kt < NHID; kt += 32) {
#pragma unroll
        for (int i = 0; i < 2; ++i) {
            int f = tid + 256 * i;
            int row = f >> 3, k4 = f & 7;
            float4 v = *(const float4*)&h[(size_t)(row0 + row) * NHID + kt + k4 * 4];
            ushort4 hh, ll;
            hh.x = f2bf(v.x); ll.x = f2bf(v.x - bf2f(hh.x));
            hh.y = f2bf(v.y); ll.y = f2bf(v.y - bf2f(hh.y));
            hh.z = f2bf(v.z); ll.z = f2bf(v.z - bf2f(hh.z));
            hh.w = f2bf(v.w); ll.w = f2bf(v.w - bf2f(hh.w));
            *(ushort4*)&Ah[row * ASTR + k4 * 4] = hh;
            *(ushort4*)&Al[row * ASTR + k4 * 4] = ll;
        }
        __syncthreads();
        int ar_ = w * 16 + m16;
        bf16x8 ah  = *(const bf16x8*)&Ah[ar_ * ASTR + kblk * 8];
        bf16x8 alo = *(const bf16x8*)&Al[ar_ * ASTR + kblk * 8];
#pragma unroll
        for (int nr = 0; nr < 3; ++nr) {
            int br = nr * 16 + m16;
            bf16x8 bh = *(const bf16x8*)&Bh[br * OBSTR + kt + kblk * 8];
            bf16x8 bl = *(const bf16x8*)&Bl[br * OBSTR + kt + kblk * 8];
            acc[nr] = __builtin_amdgcn_mfma_f32_16x16x32_bf16(ah,  bh, acc[nr], 0, 0, 0);
            acc[nr] = __builtin_amdgcn_mfma_f32_16x16x32_bf16(ah,  bl, acc[nr], 0, 0, 0);
            acc[nr] = __builtin_amdgcn_mfma_f32_16x16x32_bf16(alo, bh, acc[nr], 0, 0, 0);
        }
        __syncthreads();
    }
#pragma unroll
    for (int nr = 0; nr < 3; ++nr) {
        int col = nr * 16 + m16;
        if (col < NCLASS) {
            float bias = be[col];
#pragma unroll
            for (int r = 0; r < 4; ++r) {
                int row = row0 + w * 16 + kblk * 4 + r;
                out[(size_t)row * NCLASS + col] = (acc[nr][r] + bias) * top[row];
            }
        }
    }
}

extern "C" void kernel_launch(void* const* d_in, const int* in_sizes, int n_in,
                              void* d_out, int out_size, void* d_ws, size_t ws_size,
                              hipStream_t stream) {
    const float* x     = (const float*)d_in[0];
    const int*   ei    = (const int*)d_in[1];
    const float* eattr = (const float*)d_in[2];
    const float* Ws    = (const float*)d_in[3];
    const float* bs    = (const float*)d_in[4];
    const float* attl  = (const float*)d_in[5];
    const float* attr_ = (const float*)d_in[6];
    const float* We    = (const float*)d_in[7];
    const float* be    = (const float*)d_in[8];
    float* out = (float*)d_out;

    char* ws = (char*)d_ws;
    const size_t HB = (size_t)N_NODES * NHID * sizeof(float);   // 32 MB
    float* hA  = (float*)(ws);
    float* hB  = (float*)(ws + HB);
    float* h0  = (float*)(ws + 2 * HB);
    char* sm = ws + 3 * HB;
    float* al       = (float*)(sm);               sm += 131072;
    float* ar       = (float*)(sm);               sm += 131072;
    float* nrm      = (float*)(sm);               sm += 131072;
    float* top      = (float*)(sm);               sm += 131072;
    int*   cnt      = (int*)(sm);                 sm += 131072;
    int*   cur      = (int*)(sm);                 sm += 131072;
    int*   off      = (int*)(sm);                 sm += 262144;  // 32769 ints
    int*   csr_src  = (int*)(sm);                 sm += E_EDGES * 4;
    int*   csr_dst  = (int*)(sm);                 sm += E_EDGES * 4;
    float* csr_w    = (float*)(sm);               sm += E_EDGES * 4;
    float* csr_coef = (float*)(sm);               sm += E_EDGES * 4;
    unsigned short* Whi = (unsigned short*)(sm);  sm += NHID * NFEAT * 2;
    unsigned short* Wlo = (unsigned short*)(sm);  sm += NHID * NFEAT * 2;

    const int* srcp = ei;
    const int* dstp = ei + E_EDGES;

    init_kernel<<<N_NODES / 256, 256, 0, stream>>>(top, cnt, cur);
    count_kernel<<<E_EDGES / 256, 256, 0, stream>>>(dstp, cnt);
    scan_kernel<<<1, 1024, 0, stream>>>(cnt, off);
    scatter_kernel<<<E_EDGES / 256, 256, 0, stream>>>(srcp, dstp, eattr, off, cur,
                                                      csr_src, csr_dst, csr_w);

    wsplit_kernel<<<(NHID * NFEAT / 4) / 256, 256, 0, stream>>>(Ws, Whi, Wlo);
    gemm_mfma32<<<(N_NODES / 128) * 2, 256, 0, stream>>>(x, Whi, Wlo, bs, h0);

    // layer-0 attention dots on h0
    dots_kernel<<<N_NODES / 4, 256, 0, stream>>>(h0, attl, attr_, al, ar);

    float* hin = h0;
    float* hout = hA;
    for (int l = 0; l < 2; ++l) {
        coefcsr_kernel<<<E_EDGES / 256, 256, 0, stream>>>(csr_src, csr_dst, csr_w,
                                                          top, al, ar, csr_coef);
        int want_dots = (l == 0) ? 1 : 0;
        gather_kernel<<<N_NODES / 4, 256, 0, stream>>>(csr_src, off, csr_coef,
                                                       hin, h0, top, hout, nrm,
                                                       attl + NHID, attr_ + NHID,
                                                       al, ar, want_dots);
        int drop_from = (l == 0) ? 256 : 128;
        topk_kernel<<<WLEN, VLEN, 0, stream>>>(nrm, top, drop_from);
        hin = hout;
        hout = (hout == hA) ? hB : hA;
    }

    out_mfma<<<N_NODES / 64, 256, 0, stream>>>(hin, We, be, top, out);
}